// Round 14
// baseline (225.201 us; speedup 1.0000x reference)
//
#include <hip/hip_runtime.h>
#include <hip/hip_bf16.h>

// ---------------- types ----------------
typedef __bf16 bf16x8 __attribute__((ext_vector_type(8)));
typedef __bf16 bf16x4 __attribute__((ext_vector_type(4)));
typedef float  f32x4  __attribute__((ext_vector_type(4)));
typedef float  f32x4u __attribute__((ext_vector_type(4), aligned(4)));

// ---------------- problem constants ----------------
#define NSOL  1027
#define IND   257
#define OUT_SRC  0ULL
#define OUT_CAND 32768ULL
#define OUT_DST  33587200ULL
#define OUT_DEP  33619968ULL

// LDS tile buffer: 32 rows x 264 bf16 (528 B stride; 528 mod 256 == 16 ->
// ~2-way-max bank pattern for ds_read_b128 / ds_write_b64) + 32 f32 (k=256 col)
#define XST_B      528
#define X256_OFF_B 16896
#define BUF_B      17024     // one tile buffer; ring of 4 = 68096 B LDS

// raw barrier: drain LDS ops only — in-flight global loads/stores unaffected
#define BARRIER() { asm volatile("s_waitcnt lgkmcnt(0)" ::: "memory"); \
  __builtin_amdgcn_s_barrier(); asm volatile("" ::: "memory"); }

// issue one 32-row tile's loads into regs (512 thr: wave w stages rows 4w..4w+3)
#define ISSUE(xb, xstr, pf, pf256) { \
  _Pragma("unroll") for (int rr = 0; rr < 4; ++rr) \
    pf[rr] = *((const f32x4u*)((xb) + (size_t)(wave * 4 + rr) * (xstr)) + lane); \
  if (tid < 32) pf256 = (xb)[(size_t)tid * (xstr) + 256]; }

// convert + write a staged tile into LDS at byte offset boff
#define WRITEB(boff, pf, pf256) { \
  _Pragma("unroll") for (int rr = 0; rr < 4; ++rr) { \
    const int r_ = wave * 4 + rr; \
    bf16x4 h_; \
    h_[0] = (__bf16)pf[rr][0]; h_[1] = (__bf16)pf[rr][1]; \
    h_[2] = (__bf16)pf[rr][2]; h_[3] = (__bf16)pf[rr][3]; \
    *(bf16x4*)(smem + (boff) + r_ * XST_B + lane * 8) = h_; } \
  if (tid < 32) *(float*)(smem + (boff) + X256_OFF_B + tid * 4) = pf256; }

// build this wave's W_eff MFMA-A fragments + bias + k=256 column in registers
// (raw W arrays are L2/L3-hot; fully overlapped with outstanding X loads)
#define BUILD_W() { \
  _Pragma("unroll") for (int n = 0; n < 2; ++n) { \
    const int e_ = wave * 32 + n * 16 + rl; \
    const float* pc_ = Wseg + (size_t)e_ * IND; \
    const float* pr_ = Wrg  + (size_t)e_ * IND; \
    const float* pd_ = Wrnd + (size_t)e_ * IND; \
    _Pragma("unroll") for (int kk = 0; kk < 8; ++kk) { \
      const int k0_ = kk * 32 + grp * 8; \
      f32x4 c0 = *(const f32x4u*)(pc_ + k0_), c1 = *(const f32x4u*)(pc_ + k0_ + 4); \
      f32x4 r0 = *(const f32x4u*)(pr_ + k0_), r1 = *(const f32x4u*)(pr_ + k0_ + 4); \
      f32x4 d0 = *(const f32x4u*)(pd_ + k0_), d1 = *(const f32x4u*)(pd_ + k0_ + 4); \
      bf16x8 wv_; \
      _Pragma("unroll") for (int j = 0; j < 4; ++j) { \
        wv_[j]     = (__bf16)(ca * c0[j] + a * r0[j] + sa * d0[j]); \
        wv_[j + 4] = (__bf16)(ca * c1[j] + a * r1[j] + sa * d1[j]); } \
      wreg[kk][n] = wv_; } } \
  _Pragma("unroll") for (int n = 0; n < 2; ++n) { \
    const int e0_ = wave * 32 + n * 16 + grp * 4; \
    f32x4 bs_ = *(const f32x4u*)(Bseg + e0_); \
    f32x4 br_ = *(const f32x4u*)(brg + e0_); \
    _Pragma("unroll") for (int j = 0; j < 4; ++j) { \
      const size_t si_ = (size_t)(e0_ + j) * IND + 256; \
      b4[n][j] = ca * bs_[j] + a * br_[j]; \
      w4[n][j] = ca * Wseg[si_] + a * Wrg[si_] + sa * Wrnd[si_]; } } }

// compute one tile from LDS (register-resident W; no global loads) + nt-store
#define COMPSTORE(boff, obase) { \
  f32x4 acc[2][2]; \
  _Pragma("unroll") for (int rt = 0; rt < 2; ++rt) \
    _Pragma("unroll") for (int n = 0; n < 2; ++n) { f32x4 z_ = {0.f,0.f,0.f,0.f}; acc[rt][n] = z_; } \
  _Pragma("unroll") for (int kk = 0; kk < 8; ++kk) { \
    bf16x8 a0 = *(const bf16x8*)(smem + (boff) + rl * XST_B + kk * 64 + grp * 16); \
    bf16x8 a1 = *(const bf16x8*)(smem + (boff) + (16 + rl) * XST_B + kk * 64 + grp * 16); \
    _Pragma("unroll") for (int n = 0; n < 2; ++n) { \
      acc[0][n] = __builtin_amdgcn_mfma_f32_16x16x32_bf16(wreg[kk][n], a0, acc[0][n], 0, 0, 0); \
      acc[1][n] = __builtin_amdgcn_mfma_f32_16x16x32_bf16(wreg[kk][n], a1, acc[1][n], 0, 0, 0); } } \
  _Pragma("unroll") for (int rt = 0; rt < 2; ++rt) { \
    const float xl = *(const float*)(smem + (boff) + X256_OFF_B + (rt * 16 + rl) * 4); \
    float* op_ = (obase) + (size_t)(rt * 16 + rl) * 256 + wave * 32 + grp * 4; \
    _Pragma("unroll") for (int n = 0; n < 2; ++n) { \
      f32x4 r_ = acc[rt][n] + xl * w4[n] + b4[n]; \
      __builtin_nontemporal_store(r_, (f32x4*)(op_ + n * 16)); } } }

__device__ __forceinline__ const float* cand_x(const float* sol, int T) {
    const int bb = T >> 5, t = T & 31;
    return sol + ((size_t)bb * NSOL + 1 + t * 32) * IND;
}
__device__ __forceinline__ float* cand_o(float* out, int T) {
    const int bb = T >> 5, t = T & 31;
    return out + OUT_CAND + ((size_t)bb * 1024 + t * 32) * 256;
}

// ---- fused single kernel: 12 edge blocks + 512 uniform 8-tile cand blocks ----
__global__ __launch_bounds__(512, 2) void swne_fused(
    const float* __restrict__ sol,
    const float* __restrict__ Wsrc, const float* __restrict__ bsrc,
    const float* __restrict__ Wdst, const float* __restrict__ bdst,
    const float* __restrict__ Wdep, const float* __restrict__ bdep,
    const float* __restrict__ Wcand, const float* __restrict__ bcand,
    const float* __restrict__ Wrg, const float* __restrict__ brg,
    const float* __restrict__ Wrnd, const float* __restrict__ iw,
    float* __restrict__ out)
{
    __shared__ __align__(16) char smem[4 * BUF_B];   // 68 KiB ring of 4 tile buffers
    const int tid = threadIdx.x, bid = blockIdx.x;
    const int lane = tid & 63, wave = tid >> 6;      // 8 waves, wave owns 32 e-cols
    const int rl = lane & 15, grp = lane >> 4;

    const float a  = 1.0f / (1.0f + expf(-iw[0]));   // sigmoid(integration_weight)
    const float ca = 1.0f - a;
    const float sa = 0.1f * a;

    bf16x8 wreg[8][2];
    f32x4 b4[2], w4[2];
    f32x4 pfA[4], pfB[4];
    float pA256 = 0.f, pB256 = 0.f;

    if (bid < 12) {
        // ---- edge block: one 32-batch edge tile (src/dst/dep x 32-batch group) ----
        const int s3 = bid >> 2, tt = bid & 3;       // 0:src 1:dst 2:dep
        const int nrow = (s3 == 0) ? 0 : (s3 == 1 ? 1025 : 1026);
        const size_t outb = (s3 == 0) ? OUT_SRC : (s3 == 1 ? OUT_DST : OUT_DEP);
        const float* Wseg = (s3 == 0) ? Wsrc : (s3 == 1 ? Wdst : Wdep);
        const float* Bseg = (s3 == 0) ? bsrc : (s3 == 1 ? bdst : bdep);
        const float* xe = sol + ((size_t)(tt * 32) * NSOL + nrow) * IND;
        float* oe = out + outb + (size_t)(tt * 32) * 256;
        const size_t xstrE = (size_t)NSOL * IND;

        ISSUE(xe, xstrE, pfA, pA256);                // HBM first
        BUILD_W();                                   // overlapped with X latency
        WRITEB(0, pfA, pA256);
        BARRIER();
        COMPSTORE(0, oe);
        return;
    }

    // ---- candidate block: uniform 8 tiles, ring-4 LDS, 2-deep reg prefetch ----
    const float* Wseg = Wcand;
    const float* Bseg = bcand;
    const int T0 = (bid - 12) * 8;

    // X-tile HBM loads first — memory system starts at cycle 0
    ISSUE(cand_x(sol, T0 + 0), IND, pfA, pA256);
    ISSUE(cand_x(sol, T0 + 1), IND, pfB, pB256);

    BUILD_W();                                       // W_eff frags built under X latency

    // tiles -> buffers: t(i) -> buf(i & 3)
    WRITEB(0 * BUF_B, pfA, pA256);
    WRITEB(1 * BUF_B, pfB, pB256);
    ISSUE(cand_x(sol, T0 + 2), IND, pfA, pA256);
    ISSUE(cand_x(sol, T0 + 3), IND, pfB, pB256);
    BARRIER();

    // phase 0: compute t0,t1; write t2,t3; issue t4,t5
    COMPSTORE((size_t)0 * BUF_B, cand_o(out, T0 + 0));
    WRITEB((size_t)2 * BUF_B, pfA, pA256);
    ISSUE(cand_x(sol, T0 + 4), IND, pfA, pA256);
    COMPSTORE((size_t)1 * BUF_B, cand_o(out, T0 + 1));
    WRITEB((size_t)3 * BUF_B, pfB, pB256);
    ISSUE(cand_x(sol, T0 + 5), IND, pfB, pB256);
    BARRIER();

    // phase 1: compute t2,t3; write t4,t5; issue t6,t7
    COMPSTORE((size_t)2 * BUF_B, cand_o(out, T0 + 2));
    WRITEB((size_t)0 * BUF_B, pfA, pA256);
    ISSUE(cand_x(sol, T0 + 6), IND, pfA, pA256);
    COMPSTORE((size_t)3 * BUF_B, cand_o(out, T0 + 3));
    WRITEB((size_t)1 * BUF_B, pfB, pB256);
    ISSUE(cand_x(sol, T0 + 7), IND, pfB, pB256);
    BARRIER();

    // phase 2: compute t4,t5; write t6,t7
    COMPSTORE((size_t)0 * BUF_B, cand_o(out, T0 + 4));
    WRITEB((size_t)2 * BUF_B, pfA, pA256);
    COMPSTORE((size_t)1 * BUF_B, cand_o(out, T0 + 5));
    WRITEB((size_t)3 * BUF_B, pfB, pB256);
    BARRIER();

    // phase 3: compute t6,t7
    COMPSTORE((size_t)2 * BUF_B, cand_o(out, T0 + 6));
    COMPSTORE((size_t)3 * BUF_B, cand_o(out, T0 + 7));
}

extern "C" void kernel_launch(void* const* d_in, const int* in_sizes, int n_in,
                              void* d_out, int out_size, void* d_ws, size_t ws_size,
                              hipStream_t stream) {
    const float* sol   = (const float*)d_in[0];
    const float* Wsrc  = (const float*)d_in[1];
    const float* bsrc  = (const float*)d_in[2];
    const float* Wdst  = (const float*)d_in[3];
    const float* bdst  = (const float*)d_in[4];
    const float* Wdep  = (const float*)d_in[5];
    const float* bdep  = (const float*)d_in[6];
    const float* Wcand = (const float*)d_in[7];
    const float* bcand = (const float*)d_in[8];
    const float* Wreg  = (const float*)d_in[9];
    const float* breg  = (const float*)d_in[10];
    const float* Wrand = (const float*)d_in[11];
    const float* iw    = (const float*)d_in[12];

    swne_fused<<<524, 512, 0, stream>>>(sol, Wsrc, bsrc, Wdst, bdst, Wdep, bdep,
                                        Wcand, bcand, Wreg, breg, Wrand, iw,
                                        (float*)d_out);
}

// Round 15
// 63.401 us; speedup vs baseline: 3.5520x; 3.5520x over previous
//
#include <hip/hip_runtime.h>
#include <hip/hip_bf16.h>

// ---------------- types ----------------
typedef __bf16 bf16x8 __attribute__((ext_vector_type(8)));
typedef __bf16 bf16x4 __attribute__((ext_vector_type(4)));
typedef float  f32x4  __attribute__((ext_vector_type(4)));
typedef float  f32x4u __attribute__((ext_vector_type(4), aligned(4)));

// ---------------- problem constants ----------------
#define BATCH 128
#define NSOL  1027
#define IND   257
#define EMB   256
#define OUT_SRC  0ULL
#define OUT_CAND 32768ULL
#define OUT_DST  33587200ULL
#define OUT_DEP  33619968ULL

// workspace layout (bytes)
// W_eff bf16 MFMA-A-frag order, ALL 4 segs: [seg][kk(8)][cg(16)][lane(64)][j(8)]
#define WFRAG_OFF 0
#define BEFF_OFF  524288     // b_eff fp32 [4][256]
#define W256_OFF  528384     // W_eff[:,k=256] fp32 [4][256]

// LDS tile buffer: 32 rows x 264 bf16 (528 B stride; 528 mod 256 == 16 ->
// ~2-way-max bank pattern for ds_read_b128 / ds_write_b64) + 32 f32 (k=256 col)
#define XST_B      528
#define X256_OFF_B 16896
#define BUF_B      17024     // one tile buffer; ring of 4 = 68096 B LDS

// ---------------- prep: build effective weights ----------------
__global__ __launch_bounds__(256) void swne_prep(
    const float* __restrict__ Wsrc, const float* __restrict__ bsrc,
    const float* __restrict__ Wdst, const float* __restrict__ bdst,
    const float* __restrict__ Wdep, const float* __restrict__ bdep,
    const float* __restrict__ Wcand, const float* __restrict__ bcand,
    const float* __restrict__ Wreg, const float* __restrict__ breg,
    const float* __restrict__ Wrand, const float* __restrict__ iw,
    char* __restrict__ ws)
{
    const float a  = 1.0f / (1.0f + expf(-iw[0]));
    const float ca = 1.0f - a;
    const float sa = 0.1f * a;

    const float* Ws[4] = {Wsrc, Wcand, Wdst, Wdep};
    const float* Bs[4] = {bsrc, bcand, bdst, bdep};

    const int gid = blockIdx.x * 256 + threadIdx.x;
    const int gsz = gridDim.x * 256;

    float* beff = (float*)(ws + BEFF_OFF);
    float* w256 = (float*)(ws + W256_OFF);
    for (int i = gid; i < 4 * EMB; i += gsz) {
        int seg = i >> 8, e = i & 255;
        beff[i] = ca * Bs[seg][e] + a * breg[e];
        int si = e * IND + 256;
        w256[i] = ca * Ws[seg][si] + a * Wreg[si] + sa * Wrand[si];
    }

    // W_eff bf16 MFMA-A-frag order for all 4 segs, k = 0..255
    __bf16* wfr = (__bf16*)(ws + WFRAG_OFF);
    for (int i = gid; i < 4 * 65536; i += gsz) {
        int seg  = i >> 16;
        int rem  = i & 65535;
        int kk   = rem >> 13;
        int rem2 = rem & 8191;
        int cg   = rem2 >> 9;
        int rem3 = rem2 & 511;
        int l    = rem3 >> 3;
        int j    = rem3 & 7;
        int e = cg * 16 + (l & 15);
        int k = kk * 32 + (l >> 4) * 8 + j;
        int si = e * IND + k;
        wfr[i] = (__bf16)(ca * Ws[seg][si] + a * Wreg[si] + sa * Wrand[si]);
    }
}

// raw barrier: drain LDS ops only — in-flight global loads/stores unaffected
#define BARRIER() { asm volatile("s_waitcnt lgkmcnt(0)" ::: "memory"); \
  __builtin_amdgcn_s_barrier(); asm volatile("" ::: "memory"); }

// issue one 32-row tile's loads into regs (512 thr: wave w stages rows 4w..4w+3)
#define ISSUE(xb, xstr, pf, pf256) { \
  _Pragma("unroll") for (int rr = 0; rr < 4; ++rr) \
    pf[rr] = *((const f32x4u*)((xb) + (size_t)(wave * 4 + rr) * (xstr)) + lane); \
  if (tid < 32) pf256 = (xb)[(size_t)tid * (xstr) + 256]; }

// convert + write a staged tile into LDS at byte offset boff
#define WRITEB(boff, pf, pf256) { \
  _Pragma("unroll") for (int rr = 0; rr < 4; ++rr) { \
    const int r_ = wave * 4 + rr; \
    bf16x4 h_; \
    h_[0] = (__bf16)pf[rr][0]; h_[1] = (__bf16)pf[rr][1]; \
    h_[2] = (__bf16)pf[rr][2]; h_[3] = (__bf16)pf[rr][3]; \
    *(bf16x4*)(smem + (boff) + r_ * XST_B + lane * 8) = h_; } \
  if (tid < 32) *(float*)(smem + (boff) + X256_OFF_B + tid * 4) = pf256; }

// compute one tile from LDS (register-resident W; no global loads) + nt-store
#define COMPSTORE(boff, obase, W, B4, W4) { \
  f32x4 acc[2][2]; \
  _Pragma("unroll") for (int rt = 0; rt < 2; ++rt) \
    _Pragma("unroll") for (int n = 0; n < 2; ++n) { f32x4 z_ = {0.f,0.f,0.f,0.f}; acc[rt][n] = z_; } \
  _Pragma("unroll") for (int kk = 0; kk < 8; ++kk) { \
    bf16x8 a0 = *(const bf16x8*)(smem + (boff) + rl * XST_B + kk * 64 + grp * 16); \
    bf16x8 a1 = *(const bf16x8*)(smem + (boff) + (16 + rl) * XST_B + kk * 64 + grp * 16); \
    _Pragma("unroll") for (int n = 0; n < 2; ++n) { \
      acc[0][n] = __builtin_amdgcn_mfma_f32_16x16x32_bf16(W[kk][n], a0, acc[0][n], 0, 0, 0); \
      acc[1][n] = __builtin_amdgcn_mfma_f32_16x16x32_bf16(W[kk][n], a1, acc[1][n], 0, 0, 0); } } \
  _Pragma("unroll") for (int rt = 0; rt < 2; ++rt) { \
    const float xl = *(const float*)(smem + (boff) + X256_OFF_B + (rt * 16 + rl) * 4); \
    float* op_ = (obase) + (size_t)(rt * 16 + rl) * 256 + wave * 32 + grp * 4; \
    _Pragma("unroll") for (int n = 0; n < 2; ++n) { \
      f32x4 r_ = acc[rt][n] + xl * W4[n] + B4[n]; \
      __builtin_nontemporal_store(r_, (f32x4*)(op_ + n * 16)); } } }

__device__ __forceinline__ const float* cand_x(const float* sol, int T) {
    const int bb = T >> 5, t = T & 31;
    return sol + ((size_t)bb * NSOL + 1 + t * 32) * IND;
}
__device__ __forceinline__ float* cand_o(float* out, int T) {
    const int bb = T >> 5, t = T & 31;
    return out + OUT_CAND + ((size_t)bb * 1024 + t * 32) * 256;
}

// ---- main: 12 single-tile edge blocks (first) + 512 uniform 8-tile cand blocks ----
__global__ __launch_bounds__(512, 2) void swne_main(const float* __restrict__ sol,
                                                    const char* __restrict__ ws,
                                                    float* __restrict__ out)
{
    __shared__ __align__(16) char smem[4 * BUF_B];   // 68 KiB ring of 4 tile buffers
    const int tid = threadIdx.x, bid = blockIdx.x;
    const int lane = tid & 63, wave = tid >> 6;      // 8 waves, wave owns 32 e-cols
    const int rl = lane & 15, grp = lane >> 4;

    const bf16x8* wfb = (const bf16x8*)(ws + WFRAG_OFF);
    f32x4 pfA[4], pfB[4], pfC[4];
    float pA256 = 0.f, pB256 = 0.f, pC256 = 0.f;

    if (bid < 12) {
        // ---- edge block: one 32-batch edge tile (src/dst/dep x 32-batch group) ----
        const int s3 = bid >> 2, tt = bid & 3;       // 0:src 1:dst 2:dep
        const int seg = (s3 == 0) ? 0 : (s3 == 1 ? 2 : 3);
        const int nrow = (s3 == 0) ? 0 : (s3 == 1 ? 1025 : 1026);
        const size_t outb = (s3 == 0) ? OUT_SRC : (s3 == 1 ? OUT_DST : OUT_DEP);
        const float* xe = sol + ((size_t)(tt * 32) * NSOL + nrow) * IND;
        float* oe = out + outb + (size_t)(tt * 32) * 256;
        const size_t xstrE = (size_t)NSOL * IND;

        ISSUE(xe, xstrE, pfA, pA256);                // HBM first

        bf16x8 wregE[8][2];
        #pragma unroll
        for (int kk = 0; kk < 8; ++kk)
            #pragma unroll
            for (int n = 0; n < 2; ++n)
                wregE[kk][n] = wfb[(size_t)(((seg * 8 + kk) * 16) + (wave * 2 + n)) * 64 + lane];
        const float* bcE = (const float*)(ws + BEFF_OFF) + seg * 256;
        const float* wcE = (const float*)(ws + W256_OFF) + seg * 256;
        f32x4 b4E[2], w4E[2];
        #pragma unroll
        for (int n = 0; n < 2; ++n) {
            b4E[n] = *(const f32x4*)(bcE + wave * 32 + n * 16 + grp * 4);
            w4E[n] = *(const f32x4*)(wcE + wave * 32 + n * 16 + grp * 4);
        }

        WRITEB(0, pfA, pA256);
        BARRIER();
        COMPSTORE(0, oe, wregE, b4E, w4E);
        return;
    }

    // ---- candidate block: uniform 8 tiles, ring-4 LDS, 3-deep reg prefetch ----
    const int T0 = (bid - 12) * 8;

    // HBM loads for tiles 0..2 first — memory system starts at cycle 0
    ISSUE(cand_x(sol, T0 + 0), IND, pfA, pA256);
    ISSUE(cand_x(sol, T0 + 1), IND, pfB, pB256);
    ISSUE(cand_x(sol, T0 + 2), IND, pfC, pC256);

    // cand (seg=1) W fragments resident: 16 x bf16x8 = 64 VGPR (L2-hot)
    bf16x8 wreg[8][2];
    #pragma unroll
    for (int kk = 0; kk < 8; ++kk)
        #pragma unroll
        for (int n = 0; n < 2; ++n)
            wreg[kk][n] = wfb[(size_t)(((8 + kk) * 16) + (wave * 2 + n)) * 64 + lane];

    const float* bc = (const float*)(ws + BEFF_OFF) + 256;   // seg 1
    const float* wc = (const float*)(ws + W256_OFF) + 256;
    f32x4 b4[2], w4[2];
    #pragma unroll
    for (int n = 0; n < 2; ++n) {
        b4[n] = *(const f32x4*)(bc + wave * 32 + n * 16 + grp * 4);
        w4[n] = *(const f32x4*)(wc + wave * 32 + n * 16 + grp * 4);
    }

    // tiles -> buffers: t(i) -> buf(i & 3)
    WRITEB(0 * BUF_B, pfA, pA256);
    WRITEB(1 * BUF_B, pfB, pB256);
    ISSUE(cand_x(sol, T0 + 3), IND, pfA, pA256);
    ISSUE(cand_x(sol, T0 + 4), IND, pfB, pB256);
    BARRIER();

    // phase 0: compute t0,t1; write t2,t3; issue t5,t6
    COMPSTORE((size_t)0 * BUF_B, cand_o(out, T0 + 0), wreg, b4, w4);
    WRITEB((size_t)2 * BUF_B, pfC, pC256);
    ISSUE(cand_x(sol, T0 + 5), IND, pfC, pC256);
    COMPSTORE((size_t)1 * BUF_B, cand_o(out, T0 + 1), wreg, b4, w4);
    WRITEB((size_t)3 * BUF_B, pfA, pA256);
    ISSUE(cand_x(sol, T0 + 6), IND, pfA, pA256);
    BARRIER();

    // phase 1: compute t2,t3; write t4,t5; issue t7
    COMPSTORE((size_t)2 * BUF_B, cand_o(out, T0 + 2), wreg, b4, w4);
    WRITEB((size_t)0 * BUF_B, pfB, pB256);
    ISSUE(cand_x(sol, T0 + 7), IND, pfB, pB256);
    COMPSTORE((size_t)3 * BUF_B, cand_o(out, T0 + 3), wreg, b4, w4);
    WRITEB((size_t)1 * BUF_B, pfC, pC256);
    BARRIER();

    // phase 2: compute t4,t5; write t6,t7
    COMPSTORE((size_t)0 * BUF_B, cand_o(out, T0 + 4), wreg, b4, w4);
    WRITEB((size_t)2 * BUF_B, pfA, pA256);
    COMPSTORE((size_t)1 * BUF_B, cand_o(out, T0 + 5), wreg, b4, w4);
    WRITEB((size_t)3 * BUF_B, pfB, pB256);
    BARRIER();

    // phase 3: compute t6,t7
    COMPSTORE((size_t)2 * BUF_B, cand_o(out, T0 + 6), wreg, b4, w4);
    COMPSTORE((size_t)3 * BUF_B, cand_o(out, T0 + 7), wreg, b4, w4);
}

extern "C" void kernel_launch(void* const* d_in, const int* in_sizes, int n_in,
                              void* d_out, int out_size, void* d_ws, size_t ws_size,
                              hipStream_t stream) {
    const float* sol   = (const float*)d_in[0];
    const float* Wsrc  = (const float*)d_in[1];
    const float* bsrc  = (const float*)d_in[2];
    const float* Wdst  = (const float*)d_in[3];
    const float* bdst  = (const float*)d_in[4];
    const float* Wdep  = (const float*)d_in[5];
    const float* bdep  = (const float*)d_in[6];
    const float* Wcand = (const float*)d_in[7];
    const float* bcand = (const float*)d_in[8];
    const float* Wreg  = (const float*)d_in[9];
    const float* breg  = (const float*)d_in[10];
    const float* Wrand = (const float*)d_in[11];
    const float* iw    = (const float*)d_in[12];

    swne_prep<<<2048, 256, 0, stream>>>(Wsrc, bsrc, Wdst, bdst, Wdep, bdep,
                                        Wcand, bcand, Wreg, breg, Wrand, iw,
                                        (char*)d_ws);
    swne_main<<<524, 512, 0, stream>>>(sol, (const char*)d_ws, (float*)d_out);
}